// Round 7
// baseline (209.391 us; speedup 1.0000x reference)
//
#include <hip/hip_runtime.h>
#include <hip/hip_bf16.h>
#include <stdint.h>

typedef unsigned short u16;
typedef unsigned int u32;
typedef __bf16 bf16x8 __attribute__((ext_vector_type(8)));
typedef _Float16 f16x8 __attribute__((ext_vector_type(8)));
typedef float f32x4 __attribute__((ext_vector_type(4)));
typedef float f32x16 __attribute__((ext_vector_type(16)));
typedef unsigned short u16x4 __attribute__((ext_vector_type(4)));
typedef unsigned short u16x8 __attribute__((ext_vector_type(8)));
typedef unsigned int u32x4 __attribute__((ext_vector_type(4)));

#define SEQ     1024
#define DIM     768
#define NH      12
#define QKV_LD  2304
#define LOG2E   1.4426950408889634f
#define C1      0.18033688f   /* 0.125 * log2(e) */

__device__ __forceinline__ float bf2f(u16 u) {
    union { unsigned v; float f; } x; x.v = ((unsigned)u) << 16; return x.f;
}
__device__ __forceinline__ u16 f2bf(float f) {
    union { float f; unsigned v; } x; x.f = f;
    unsigned r = (x.v + 0x7FFFu + ((x.v >> 16) & 1u)) >> 16;
    return (u16)r;
}
__device__ __forceinline__ void store_out(u16* p, float v)  { *p = f2bf(v); }
__device__ __forceinline__ void store_out(float* p, float v){ *p = v; }

// async global->LDS, 16B per lane. HW semantics: LDS dest = wave base + lane*16.
__device__ __forceinline__ void async16(void* lds, const void* g) {
    __builtin_amdgcn_global_load_lds(
        (const __attribute__((address_space(1))) unsigned*)(uintptr_t)g,
        (__attribute__((address_space(3))) unsigned*)(unsigned)(uintptr_t)lds,
        16, 0, 0);
}

// ---------------- fp32 -> bf16 convert (x) ----------------
__global__ __launch_bounds__(256) void cvt_k(const float* __restrict__ in,
                                             u16* __restrict__ out) {
    int i = (blockIdx.x * 256 + threadIdx.x) * 4;
    float4 v = *(const float4*)(in + i);
    u16x4 o = { f2bf(v.x), f2bf(v.y), f2bf(v.z), f2bf(v.w) };
    *(u16x4*)(out + i) = o;
}

// ---------------- transpose + convert (fp32 weights -> bf16 B^T) ----------------
__global__ __launch_bounds__(256) void transpose_k(const float* __restrict__ in,
                                                   u16* __restrict__ out,
                                                   int R, int C) {
    __shared__ __align__(16) float t[32][33];
    int c0 = blockIdx.x * 32, r0 = blockIdx.y * 32;
    int tx = threadIdx.x & 31, ty = threadIdx.x >> 5;
#pragma unroll
    for (int i = 0; i < 32; i += 8)
        t[ty + i][tx] = in[(size_t)(r0 + ty + i) * C + c0 + tx];
    __syncthreads();
#pragma unroll
    for (int i = 0; i < 32; i += 8)
        out[(size_t)(c0 + ty + i) * R + r0 + tx] = f2bf(t[tx][ty + i]);
}

// ---- K fragment prep: qkv K-slice -> kfrag stream in MFMA A-operand order ----
// kfrag[((bh*16 + kt)*8 + (t*4+ks))*64 + lane] (bf16x8) =
//   K[key = kt*64 + t*32 + (lane&31)][dh = ks*16 + (lane>>5)*8 + j], j=0..7.
// attn then reads each fragment as ONE coalesced 16B/lane load (64 lanes = 1KB).
__global__ __launch_bounds__(256) void kprep_k(const u16* __restrict__ qkv,
                                               u16* __restrict__ kf) {
    __shared__ u16 t2[64][68];   // [key][dh], +4 pad (2-way b64 conflicts only)
    const int kt = blockIdx.x, bh = blockIdx.y;
    const int b = bh / NH, h = bh % NH;
    const int tid = threadIdx.x;
    const int row = tid >> 2, c0 = (tid & 3) * 16;
    const u16* src = qkv + (size_t)(b * SEQ + kt * 64 + row) * QKV_LD + 768 + h * 64 + c0;
#pragma unroll
    for (int q = 0; q < 4; ++q)
        *(u16x4*)&t2[row][c0 + q * 4] = *(const u16x4*)(src + q * 4);
    __syncthreads();
#pragma unroll
    for (int u = tid; u < 512; u += 256) {
        int f = u >> 6, lane = u & 63;
        int t = f >> 2, ks = f & 3;
        int hi = lane >> 5, l31 = lane & 31;
        const u16* p = &t2[t * 32 + l31][ks * 16 + hi * 8];
        u16x8 w = { p[0], p[1], p[2], p[3], p[4], p[5], p[6], p[7] };
        *(u16x8*)&kf[((((size_t)bh * 16 + kt) * 8 + f) * 64 + lane) * 8] = w;
    }
}

// ---- V fragment prep: qkv V-slice -> f16 vfrag stream in MFMA A-operand order --
// vfrag[((bh*16 + kt)*8 + (dt*4+kg))*64 + lane] (f16x8) =
//   V[key = kt*64 + kg*16 + (lane>>5)*8 + j][dh = dt*32 + (lane&31)], j=0..7.
__global__ __launch_bounds__(256) void vprep_k(const u16* __restrict__ qkv,
                                               _Float16* __restrict__ vf) {
    __shared__ u16 t2[64][68];   // [key][dh]
    const int kt = blockIdx.x, bh = blockIdx.y;
    const int b = bh / NH, h = bh % NH;
    const int tid = threadIdx.x;
    const int row = tid >> 2, c0 = (tid & 3) * 16;
    const u16* src = qkv + (size_t)(b * SEQ + kt * 64 + row) * QKV_LD + 1536 + h * 64 + c0;
#pragma unroll
    for (int q = 0; q < 4; ++q)
        *(u16x4*)&t2[row][c0 + q * 4] = *(const u16x4*)(src + q * 4);
    __syncthreads();
#pragma unroll
    for (int u = tid; u < 512; u += 256) {
        int c = u >> 6, lane = u & 63;
        int dt = c >> 2, kg = c & 3;
        int hi = lane >> 5, l31 = lane & 31;
        f16x8 w;
#pragma unroll
        for (int j = 0; j < 8; ++j)
            w[j] = (_Float16)bf2f(t2[kg * 16 + hi * 8 + j][dt * 32 + l31]);
        *(f16x8*)&vf[((((size_t)bh * 16 + kt) * 8 + c) * 64 + lane) * 8] = w;
    }
}

// ------- GEMM: C[M,N] = A[M,K]*Bt[N,K]^T (+fp32 bias), bf16, BK=64 ------------
// v12 swizzle FIX: v11 chunked the LINEARIZED index -> each XCD streamed ALL of
// A (measured FETCH 90MB ~= 8 XCDs x full A). Now each XCD owns an 8-m-tile
// chunk x all n, m-inner/n-outer: per-XCD fetch = A-chunk 1.57MB (L2-resident
// across the n sweep) + B 3.5MB -> ~41MB total. Requires gridDim.x % 8 == 0.
template <int HAS_BIAS, typename OUT_T>
__global__ __launch_bounds__(256) void gemm_bt(const u16* __restrict__ A,
                                               const u16* __restrict__ Bt,
                                               const float* __restrict__ bias,
                                               OUT_T* __restrict__ C,
                                               int M, int N, int K) {
    __shared__ __align__(16) u16 sA[128 * 64];
    __shared__ __align__(16) u16 sB[128 * 64];
    const int tid = threadIdx.x;
    const int lane = tid & 63;
    const int quad = lane >> 4, l16 = lane & 15;
    const int wave = tid >> 6;

    const int wgid = blockIdx.y * gridDim.x + blockIdx.x;
    const int xcd = wgid & 7, idx = wgid >> 3;
    const int CM = gridDim.x >> 3;               // m-tiles per XCD chunk
    const int m0 = (xcd * CM + idx % CM) * 128;  // m-inner
    const int n0 = (idx / CM) * 128;             // n-outer
    const int wm = (wave >> 1) * 64, wn = (wave & 1) * 64;

    const int co0 = (quad ^ (l16 & 7)) * 8;
    f32x4 acc[4][4] = {};

    for (int k0 = 0; k0 < K; k0 += 64) {
        __syncthreads();
#pragma unroll
        for (int rep = 0; rep < 4; ++rep) {
            int i = rep * 256 + tid;
            int row = i >> 3;
            int c = (i & 7) ^ (row & 7);
            async16(&sA[i * 8], A + (size_t)(m0 + row) * K + k0 + c * 8);
            async16(&sB[i * 8], Bt + (size_t)(n0 + row) * K + k0 + c * 8);
        }
        __syncthreads();

#pragma unroll
        for (int ks = 0; ks < 2; ++ks) {
            const int co = co0 ^ (ks * 32);
            bf16x8 af[4], bfr[4];
#pragma unroll
            for (int mi = 0; mi < 4; ++mi)
                af[mi] = *(const bf16x8*)&sA[(wm + mi * 16 + l16) * 64 + co];
#pragma unroll
            for (int nj = 0; nj < 4; ++nj)
                bfr[nj] = *(const bf16x8*)&sB[(wn + nj * 16 + l16) * 64 + co];
#pragma unroll
            for (int mi = 0; mi < 4; ++mi)
#pragma unroll
                for (int nj = 0; nj < 4; ++nj)
                    acc[mi][nj] = __builtin_amdgcn_mfma_f32_16x16x32_bf16(
                        af[mi], bfr[nj], acc[mi][nj], 0, 0, 0);
        }
    }

#pragma unroll
    for (int mi = 0; mi < 4; ++mi) {
#pragma unroll
        for (int nj = 0; nj < 4; ++nj) {
            int col = n0 + wn + nj * 16 + l16;
            float bv = HAS_BIAS ? bias[col] : 0.0f;
#pragma unroll
            for (int r = 0; r < 4; ++r) {
                int row = m0 + wm + mi * 16 + quad * 4 + r;
                store_out(&C[(size_t)row * N + col], acc[mi][nj][r] + bv);
            }
        }
    }
}

// ------ fused attention v12: barrier-free, K/V fragment streams from L2 -------
// v10 proved V-from-global fails on SCATTER, not concept: kprep/vprep now store
// K/V in exact MFMA A-operand fragment order, so every fragment is ONE coalesced
// 16B/lane load. No sK/sV, no async16, and NO BARRIERS in the loop (only the
// LUT-publish syncthreads) -> waves fully independent; 3 waves/SIMD hide the
// serial QK->exp->PV chain. Same-bh q-blocks share an XCD (96%8==0), so each
// 256KB K+V stream is HBM-fetched once and L2-served 32x. All MFMA/softmax
// math byte-identical to verified v8. LDS 8KB; ~155 VGPR.
__global__ __launch_bounds__(256, 3) void attn_k(const u16* __restrict__ qkv,
                                                 const u16* __restrict__ kfr,
                                                 const _Float16* __restrict__ vfr,
                                                 const float* __restrict__ bias_table,
                                                 u16* __restrict__ out) {
    __shared__ __align__(16) float sLut[2048];         // fp32 log2e*bias LUT

    const int tid = threadIdx.x;
    const int wave = tid >> 6, lane = tid & 63;
    const int l31 = lane & 31, hi = lane >> 5;
    const int bh = blockIdx.x;
    const int b = bh / NH, h = bh % NH;
    const int q0 = blockIdx.y * 128, wq = wave * 32;

    // bias LUT: lut[z] = log2e * bias[(z<=1023)?1023-z:z], z = 1023 + (i_q - j_key)
    for (int i = tid; i < 2047; i += 256)
        sLut[i] = LOG2E * bias_table[h * 2047 + (i <= 1023 ? 1023 - i : i)];

    // Q fragments: B-operand of 32x32x16_bf16 (col=q=l31, k = ks*16 + hi*8 + j)
    bf16x8 qf[4];
#pragma unroll
    for (int ks = 0; ks < 4; ++ks)
        qf[ks] = *(const bf16x8*)(qkv +
            (size_t)(b * SEQ + q0 + wq + l31) * QKV_LD + h * 64 + ks * 16 + hi * 8);

    // fragment stream bases (16B/lane units; frag (kt,f) at +(kt*8+f)*512 elems)
    const u16* kp = kfr + ((size_t)bh * 16 * 8 * 64 + lane) * 8;
    const _Float16* vp = vfr + ((size_t)bh * 16 * 8 * 64 + lane) * 8;

    const int ib0 = 1023 + q0 + wq + l31;
    const int hi4 = hi * 4;

    __syncthreads();   // publish LUT (the only barrier)

    f32x16 o[2] = {};    // O^T: row dh = dt*32 + (reg&3)+8*(reg>>2)+4*hi, col q = l31
    f32x16 osum = {};    // all rows identical = sum_key P[key][q]
    const u32x4 onebits = { 0x3C003C00u, 0x3C003C00u, 0x3C003C00u, 0x3C003C00u };
    const f16x8 ones = __builtin_bit_cast(f16x8, onebits);

    for (int kt = 0; kt < SEQ / 64; ++kt) {
        // V frags for this tile: issue FIRST (consumed last, ~600cy later)
        f16x8 vf[8];
#pragma unroll
        for (int c = 0; c < 8; ++c)
            vf[c] = *(const f16x8*)(vp + (size_t)(kt * 8 + c) * 512);

        // ---- S^T = K*Q^T (2 key-tiles) -> exp -> pack -> permlane swap ----
        f16x8 pfrag[4];   // B-frags for PV, kg = key group of 16
#pragma unroll
        for (int t = 0; t < 2; ++t) {
            bf16x8 kf4[4];
#pragma unroll
            for (int ks = 0; ks < 4; ++ks)
                kf4[ks] = *(const bf16x8*)(kp + (size_t)(kt * 8 + t * 4 + ks) * 512);
            f32x16 s = {};
#pragma unroll
            for (int ks = 0; ks < 4; ++ks)
                s = __builtin_amdgcn_mfma_f32_32x32x16_bf16(kf4[ks], qf[ks], s, 0, 0, 0);
            // key = kt*64 + t*32 + m + 8g + 4hi ; z = ib0 - key
            const int ibt = ib0 - kt * 64 - t * 32 - hi4;
            u32 wlo[4], whi[4];
#pragma unroll
            for (int g = 0; g < 4; ++g) {
                const float* bw = &sLut[ibt - 8 * g];
                float p0 = __builtin_amdgcn_exp2f(s[4 * g + 0] * C1 + bw[0]);
                float p1 = __builtin_amdgcn_exp2f(s[4 * g + 1] * C1 + bw[-1]);
                float p2 = __builtin_amdgcn_exp2f(s[4 * g + 2] * C1 + bw[-2]);
                float p3 = __builtin_amdgcn_exp2f(s[4 * g + 3] * C1 + bw[-3]);
                wlo[g] = __builtin_bit_cast(u32, __builtin_amdgcn_cvt_pkrtz(p0, p1));
                whi[g] = __builtin_bit_cast(u32, __builtin_amdgcn_cvt_pkrtz(p2, p3));
            }
            // frag kg=2t+c: W0/W1 = keys 16kg+hi*8+{0..3}, W2/W3 = +4.
            // swap(wlo[2c], wlo[2c+1]): r[0]=W0, r[1]=W2.
#pragma unroll
            for (int c = 0; c < 2; ++c) {
                auto rlo = __builtin_amdgcn_permlane32_swap(
                    wlo[2 * c], wlo[2 * c + 1], false, false);
                auto rhi = __builtin_amdgcn_permlane32_swap(
                    whi[2 * c], whi[2 * c + 1], false, false);
                u32x4 f = { rlo[0], rhi[0], rlo[1], rhi[1] };   // W0,W1,W2,W3
                pfrag[t * 2 + c] = __builtin_bit_cast(f16x8, f);
            }
        }

        // ---- osum += ones x P ; O^T += V-frag x P-frag ----
        __builtin_amdgcn_s_setprio(1);
#pragma unroll
        for (int kg = 0; kg < 4; ++kg)
            osum = __builtin_amdgcn_mfma_f32_32x32x16_f16(ones, pfrag[kg], osum, 0, 0, 0);
#pragma unroll
        for (int dt = 0; dt < 2; ++dt)
#pragma unroll
            for (int kg = 0; kg < 4; ++kg)
                o[dt] = __builtin_amdgcn_mfma_f32_32x32x16_f16(
                    vf[dt * 4 + kg], pfrag[kg], o[dt], 0, 0, 0);
        __builtin_amdgcn_s_setprio(0);
    }

    // epilogue: lane q = q0+wq+l31; dh = dt*32 + 8g + 4hi + m
    float inv = __builtin_amdgcn_rcpf(osum[0]);
    size_t rowbase = (size_t)(b * SEQ + q0 + wq + l31) * DIM + h * 64 + hi4;
#pragma unroll
    for (int dt = 0; dt < 2; ++dt) {
#pragma unroll
        for (int g = 0; g < 4; ++g) {
            u16x4 pk = { f2bf(o[dt][4 * g + 0] * inv), f2bf(o[dt][4 * g + 1] * inv),
                         f2bf(o[dt][4 * g + 2] * inv), f2bf(o[dt][4 * g + 3] * inv) };
            *(u16x4*)&out[rowbase + dt * 32 + 8 * g] = pk;
        }
    }
}

extern "C" void kernel_launch(void* const* d_in, const int* in_sizes, int n_in,
                              void* d_out, int out_size, void* d_ws, size_t ws_size,
                              hipStream_t stream) {
    const float* x          = (const float*)d_in[0];  // (8,1024,768) fp32
    const float* w_qkv      = (const float*)d_in[1];  // (768,2304) fp32
    const float* bias_table = (const float*)d_in[2];  // (12,2047) fp32
    const float* w_out      = (const float*)d_in[3];  // (768,768) fp32
    const float* b_out      = (const float*)d_in[4];  // (768,) fp32
    float* out = (float*)d_out;                       // (8,1024,768) fp32

    char* ws = (char*)d_ws;
    u16* ws_qkv        = (u16*)(ws);                   // 37,748,736 B
    u16* ws_attn       = (u16*)(ws + 37748736);        // 12,582,912 B
    u16* ws_xb         = (u16*)(ws + 50331648);        // 12,582,912 B (bf16 x, then kfrag)
    u16* ws_wqkvT      = (u16*)(ws + 62914560);        //  3,538,944 B
    u16* ws_woutT      = (u16*)(ws + 66453504);        //  1,179,648 B
    _Float16* ws_vT    = (_Float16*)(ws + 67633152);   // 12,582,912 B = vfrag (tot 80.2MB)

    cvt_k<<<8 * 1024 * 768 / 1024, 256, 0, stream>>>(x, ws_xb);
    transpose_k<<<dim3(2304 / 32, 768 / 32), 256, 0, stream>>>(w_qkv, ws_wqkvT, 768, 2304);
    transpose_k<<<dim3(768 / 32, 768 / 32), 256, 0, stream>>>(w_out, ws_woutT, 768, 768);

    // qkv = x @ w_qkv : M=8192, N=2304, K=768  (gridDim.x = 64, %8==0)
    gemm_bt<0, u16><<<dim3(8192 / 128, 2304 / 128), 256, 0, stream>>>(
        ws_xb, ws_wqkvT, nullptr, ws_qkv, 8192, 2304, 768);

    // ws_xb (bf16 x) is dead after the QKV gemm -> reuse as the K-fragment stream
    kprep_k<<<dim3(16, 96), 256, 0, stream>>>(ws_qkv, ws_xb);
    vprep_k<<<dim3(16, 96), 256, 0, stream>>>(ws_qkv, ws_vT);

    attn_k<<<dim3(8 * NH, SEQ / 128, 1), 256, 0, stream>>>(
        ws_qkv, ws_xb, ws_vT, bias_table, ws_attn);

    // out = attn @ w_out + b_out : M=8192, N=768, K=768  (gridDim.x = 64, %8==0)
    gemm_bt<1, float><<<dim3(8192 / 128, 768 / 128), 256, 0, stream>>>(
        ws_attn, ws_woutT, b_out, out, 8192, 768, 768);
}

// Round 8
// 196.769 us; speedup vs baseline: 1.0641x; 1.0641x over previous
//
#include <hip/hip_runtime.h>
#include <hip/hip_bf16.h>
#include <stdint.h>

typedef unsigned short u16;
typedef unsigned int u32;
typedef __bf16 bf16x8 __attribute__((ext_vector_type(8)));
typedef _Float16 f16x8 __attribute__((ext_vector_type(8)));
typedef float f32x4 __attribute__((ext_vector_type(4)));
typedef float f32x16 __attribute__((ext_vector_type(16)));
typedef unsigned short u16x4 __attribute__((ext_vector_type(4)));
typedef unsigned int u32x4 __attribute__((ext_vector_type(4)));

#define SEQ     1024
#define DIM     768
#define NH      12
#define QKV_LD  2304
#define LOG2E   1.4426950408889634f
#define C1      0.18033688f   /* 0.125 * log2(e) */

__device__ __forceinline__ float bf2f(u16 u) {
    union { unsigned v; float f; } x; x.v = ((unsigned)u) << 16; return x.f;
}
__device__ __forceinline__ u16 f2bf(float f) {
    union { float f; unsigned v; } x; x.f = f;
    unsigned r = (x.v + 0x7FFFu + ((x.v >> 16) & 1u)) >> 16;
    return (u16)r;
}
__device__ __forceinline__ void store_out(u16* p, float v)  { *p = f2bf(v); }
__device__ __forceinline__ void store_out(float* p, float v){ *p = v; }

// async global->LDS, 16B per lane. HW semantics: LDS dest = wave base + lane*16.
__device__ __forceinline__ void async16(void* lds, const void* g) {
    __builtin_amdgcn_global_load_lds(
        (const __attribute__((address_space(1))) unsigned*)(uintptr_t)g,
        (__attribute__((address_space(3))) unsigned*)(unsigned)(uintptr_t)lds,
        16, 0, 0);
}

// ---------------- fp32 -> bf16 convert (x) ----------------
__global__ __launch_bounds__(256) void cvt_k(const float* __restrict__ in,
                                             u16* __restrict__ out) {
    int i = (blockIdx.x * 256 + threadIdx.x) * 4;
    float4 v = *(const float4*)(in + i);
    u16x4 o = { f2bf(v.x), f2bf(v.y), f2bf(v.z), f2bf(v.w) };
    *(u16x4*)(out + i) = o;
}

// ---------------- transpose + convert (fp32 weights -> bf16 B^T) ----------------
__global__ __launch_bounds__(256) void transpose_k(const float* __restrict__ in,
                                                   u16* __restrict__ out,
                                                   int R, int C) {
    __shared__ __align__(16) float t[32][33];
    int c0 = blockIdx.x * 32, r0 = blockIdx.y * 32;
    int tx = threadIdx.x & 31, ty = threadIdx.x >> 5;
#pragma unroll
    for (int i = 0; i < 32; i += 8)
        t[ty + i][tx] = in[(size_t)(r0 + ty + i) * C + c0 + tx];
    __syncthreads();
#pragma unroll
    for (int i = 0; i < 32; i += 8)
        out[(size_t)(c0 + ty + i) * R + r0 + tx] = f2bf(t[tx][ty + i]);
}

// -------- V transpose: ws_qkv V-slice (bf16) -> vT[b][h][dh][seq] (f16) --------
__global__ __launch_bounds__(256) void vt_k(const u16* __restrict__ qkv,
                                            _Float16* __restrict__ vT) {
    __shared__ __align__(16) u16 t[32][33];
    int bh = blockIdx.z;
    int b = bh / 12, h = bh % 12;
    int key0 = blockIdx.x * 32, dh0 = blockIdx.y * 32;
    int tx = threadIdx.x & 31, ty = threadIdx.x >> 5;
#pragma unroll
    for (int i = 0; i < 32; i += 8)
        t[ty + i][tx] = qkv[(size_t)(b * SEQ + key0 + ty + i) * QKV_LD +
                            1536 + h * 64 + dh0 + tx];
    __syncthreads();
#pragma unroll
    for (int i = 0; i < 32; i += 8)
        vT[(size_t)(bh * 64 + dh0 + ty + i) * SEQ + key0 + tx] =
            (_Float16)bf2f(t[tx][ty + i]);
}

// ------- GEMM: C[M,N] = A[M,K]*Bt[N,K]^T (+fp32 bias), bf16, BK=64 ------------
// m-chunk XCD swizzle (v12 fix): each XCD owns an 8-m-tile chunk x all n,
// m-inner/n-outer -> A-chunk (1.57MB) stays L2-resident across the n sweep.
// v11's linearized chunking made every XCD stream ALL of A (FETCH 90MB).
template <int HAS_BIAS, typename OUT_T>
__global__ __launch_bounds__(256) void gemm_bt(const u16* __restrict__ A,
                                               const u16* __restrict__ Bt,
                                               const float* __restrict__ bias,
                                               OUT_T* __restrict__ C,
                                               int M, int N, int K) {
    __shared__ __align__(16) u16 sA[128 * 64];
    __shared__ __align__(16) u16 sB[128 * 64];
    const int tid = threadIdx.x;
    const int lane = tid & 63;
    const int quad = lane >> 4, l16 = lane & 15;
    const int wave = tid >> 6;

    const int wgid = blockIdx.y * gridDim.x + blockIdx.x;
    const int xcd = wgid & 7, idx = wgid >> 3;
    const int CM = gridDim.x >> 3;               // m-tiles per XCD chunk
    const int m0 = (xcd * CM + idx % CM) * 128;  // m-inner
    const int n0 = (idx / CM) * 128;             // n-outer
    const int wm = (wave >> 1) * 64, wn = (wave & 1) * 64;

    const int co0 = (quad ^ (l16 & 7)) * 8;
    f32x4 acc[4][4] = {};

    for (int k0 = 0; k0 < K; k0 += 64) {
        __syncthreads();
#pragma unroll
        for (int rep = 0; rep < 4; ++rep) {
            int i = rep * 256 + tid;
            int row = i >> 3;
            int c = (i & 7) ^ (row & 7);
            async16(&sA[i * 8], A + (size_t)(m0 + row) * K + k0 + c * 8);
            async16(&sB[i * 8], Bt + (size_t)(n0 + row) * K + k0 + c * 8);
        }
        __syncthreads();

#pragma unroll
        for (int ks = 0; ks < 2; ++ks) {
            const int co = co0 ^ (ks * 32);
            bf16x8 af[4], bfr[4];
#pragma unroll
            for (int mi = 0; mi < 4; ++mi)
                af[mi] = *(const bf16x8*)&sA[(wm + mi * 16 + l16) * 64 + co];
#pragma unroll
            for (int nj = 0; nj < 4; ++nj)
                bfr[nj] = *(const bf16x8*)&sB[(wn + nj * 16 + l16) * 64 + co];
#pragma unroll
            for (int mi = 0; mi < 4; ++mi)
#pragma unroll
                for (int nj = 0; nj < 4; ++nj)
                    acc[mi][nj] = __builtin_amdgcn_mfma_f32_16x16x32_bf16(
                        af[mi], bfr[nj], acc[mi][nj], 0, 0, 0);
        }
    }

#pragma unroll
    for (int mi = 0; mi < 4; ++mi) {
#pragma unroll
        for (int nj = 0; nj < 4; ++nj) {
            int col = n0 + wn + nj * 16 + l16;
            float bv = HAS_BIAS ? bias[col] : 0.0f;
#pragma unroll
            for (int r = 0; r < 4; ++r) {
                int row = m0 + wm + mi * 16 + quad * 4 + r;
                store_out(&C[(size_t)row * N + col], acc[mi][nj][r] + bv);
            }
        }
    }
}

// ---- fused attention v13: 3-buffer staging, CORRECT counted vmcnt (T3/T4) -----
// v11's 2-buffer vmcnt(4) was a race (the loads needed next tile were the
// NEWEST 4 at the barrier). 3 buffers + prefetch distance 2 make vmcnt(4)
// provably safe: at end-of-kt the tile-(kt+1) loads (issued at kt-1) are the
// OLDER 4 of <=8 outstanding; in-order retire => done. Tail: kt=14 waits
// vmcnt(0) (nothing newer in flight), kt=15 no barrier. 1200cy prefetch
// distance also covers HBM-cold first bh-visits. To keep 3 blocks/CU at
// 3x(8+8)KB buffers, the LUT shrinks to the per-block window actually
// addressed: z in [q0, q0+1150] -> 1151 f32 = 4.6KB. Total 53.8KB*3 <= 160KB.
// v12 lesson applied: LDS staging + global_load_lds stays (direct-L2 was +12us).
// Math byte-identical to verified v8; setprio(1) wraps the PV cluster (m191).
__global__ __launch_bounds__(256, 3) void attn_k(const u16* __restrict__ qkv,
                                                 const _Float16* __restrict__ vT,
                                                 const float* __restrict__ bias_table,
                                                 u16* __restrict__ out) {
    __shared__ __align__(16) u16 sK[3][64 * 64];       // [key][dh], chunk-swizzled
    __shared__ __align__(16) _Float16 sV[3][64 * 64];  // [dh][key], chunk-swizzled
    __shared__ __align__(16) float sLut[1152];         // windowed fp32 log2e*bias

    const int tid = threadIdx.x;
    const int wave = tid >> 6, lane = tid & 63;
    const int l31 = lane & 31, hi = lane >> 5;
    const int bh = blockIdx.x;
    const int b = bh / NH, h = bh % NH;
    const int q0 = blockIdx.y * 128, wq = wave * 32;

    // windowed LUT: sLut[i] = log2e*bias[z], z = q0 + i, i in [0,1150].
    // (global z = 1023 + (i_q - j_key); this block only touches z-q0 in [0,1150])
    for (int i = tid; i < 1151; i += 256) {
        int z = q0 + i;
        sLut[i] = LOG2E * bias_table[h * 2047 + (z <= 1023 ? 1023 - z : z)];
    }

    // Q fragments: B-operand of 32x32x16_bf16 (col=q=l31, k = ks*16 + hi*8 + j)
    bf16x8 qf[4];
#pragma unroll
    for (int ks = 0; ks < 4; ++ks)
        qf[ks] = *(const bf16x8*)(qkv +
            (size_t)(b * SEQ + q0 + wq + l31) * QKV_LD + h * 64 + ks * 16 + hi * 8);

    // staging addresses
    const u16* kgp[2];
    const _Float16* vgp[2];
    int lds_i[2];
#pragma unroll
    for (int rep = 0; rep < 2; ++rep) {
        int i = rep * 256 + wave * 64 + lane;
        int row = i >> 3;
        int c = (i & 7) ^ (row & 7);
        kgp[rep] = qkv + (size_t)(b * SEQ + row) * QKV_LD + 768 + h * 64 + c * 8;
        vgp[rep] = vT + (size_t)(bh * 64 + row) * SEQ + c * 8;
        lds_i[rep] = i * 8;
    }

    const int ibW = 1023 + wq + l31;   // window-relative bias index base
    const int hi4 = hi * 4;
    const int l7 = l31 & 7;

    // prologue: stage tiles 0 and 1 into buffers 0 and 1 (8 async16 in flight)
#pragma unroll
    for (int bf = 0; bf < 2; ++bf)
#pragma unroll
        for (int rep = 0; rep < 2; ++rep) {
            async16(&sK[bf][lds_i[rep]], kgp[rep]);
            async16(&sV[bf][lds_i[rep]], vgp[rep]);
            kgp[rep] += (size_t)64 * QKV_LD;
            vgp[rep] += 64;
        }
    // drain tile 0 (older 4), keep tile 1 in flight; publish LUT stores
    asm volatile("s_waitcnt vmcnt(4) lgkmcnt(0)" ::: "memory");
    __builtin_amdgcn_s_barrier();

    f32x16 o[2] = {};    // O^T: row dh = dt*32 + (reg&3)+8*(reg>>2)+4*hi, col q = l31
    f32x16 osum = {};    // all rows identical = sum_key P[key][q]
    const u32x4 onebits = { 0x3C003C00u, 0x3C003C00u, 0x3C003C00u, 0x3C003C00u };
    const f16x8 ones = __builtin_bit_cast(f16x8, onebits);

    int cur = 0;
    for (int kt = 0; kt < SEQ / 64; ++kt) {
        if (kt + 2 < SEQ / 64) {           // prefetch tile kt+2 into buf (cur+2)%3
            int b2 = cur + 2; if (b2 >= 3) b2 -= 3;
#pragma unroll
            for (int rep = 0; rep < 2; ++rep) {
                async16(&sK[b2][lds_i[rep]], kgp[rep]);
                async16(&sV[b2][lds_i[rep]], vgp[rep]);
                kgp[rep] += (size_t)64 * QKV_LD;
                vgp[rep] += 64;
            }
        }
        const u16* sKc = sK[cur];
        const _Float16* sVc = sV[cur];

        // ---- S^T = K*Q^T (2 key-tiles) -> exp -> pack -> permlane swap ----
        f16x8 pfrag[4];   // B-frags for PV, kg = key group of 16
#pragma unroll
        for (int t = 0; t < 2; ++t) {
            const u16* kr = sKc + (t * 32 + l31) * 64;
            f32x16 s = {};
#pragma unroll
            for (int ks = 0; ks < 4; ++ks) {
                int slot = (2 * ks + hi) ^ l7;
                bf16x8 af = *(const bf16x8*)(kr + slot * 8);
                s = __builtin_amdgcn_mfma_f32_32x32x16_bf16(af, qf[ks], s, 0, 0, 0);
            }
            // window index = ibW - kt*64 - t*32 - 4hi - 8g - r
            const int ibt = ibW - kt * 64 - t * 32 - hi4;
            u32 wlo[4], whi[4];
#pragma unroll
            for (int g = 0; g < 4; ++g) {
                const float* bw = &sLut[ibt - 8 * g];
                float p0 = __builtin_amdgcn_exp2f(s[4 * g + 0] * C1 + bw[0]);
                float p1 = __builtin_amdgcn_exp2f(s[4 * g + 1] * C1 + bw[-1]);
                float p2 = __builtin_amdgcn_exp2f(s[4 * g + 2] * C1 + bw[-2]);
                float p3 = __builtin_amdgcn_exp2f(s[4 * g + 3] * C1 + bw[-3]);
                wlo[g] = __builtin_bit_cast(u32, __builtin_amdgcn_cvt_pkrtz(p0, p1));
                whi[g] = __builtin_bit_cast(u32, __builtin_amdgcn_cvt_pkrtz(p2, p3));
            }
            // frag kg=2t+c: W0/W1 = keys 16kg+hi*8+{0..3}, W2/W3 = +4.
            // swap(wlo[2c], wlo[2c+1]): r[0]=W0, r[1]=W2.
#pragma unroll
            for (int c = 0; c < 2; ++c) {
                auto rlo = __builtin_amdgcn_permlane32_swap(
                    wlo[2 * c], wlo[2 * c + 1], false, false);
                auto rhi = __builtin_amdgcn_permlane32_swap(
                    whi[2 * c], whi[2 * c + 1], false, false);
                u32x4 f = { rlo[0], rhi[0], rlo[1], rhi[1] };   // W0,W1,W2,W3
                pfrag[t * 2 + c] = __builtin_bit_cast(f16x8, f);
            }
        }

        // ---- osum += ones x P ; O^T += V^T-frag x P-frag ----
        __builtin_amdgcn_s_setprio(1);
#pragma unroll
        for (int kg = 0; kg < 4; ++kg)
            osum = __builtin_amdgcn_mfma_f32_32x32x16_f16(ones, pfrag[kg], osum, 0, 0, 0);
#pragma unroll
        for (int dt = 0; dt < 2; ++dt) {
            const _Float16* vr = sVc + (dt * 32 + l31) * 64;
#pragma unroll
            for (int kg = 0; kg < 4; ++kg) {
                int slot = (2 * kg + hi) ^ l7;
                f16x8 vf = *(const f16x8*)(vr + slot * 8);
                o[dt] = __builtin_amdgcn_mfma_f32_32x32x16_f16(vf, pfrag[kg], o[dt], 0, 0, 0);
            }
        }
        __builtin_amdgcn_s_setprio(0);

        // counted barrier: tile kt+1's loads (issued at kt-1) are the OLDER 4
        // of <=8 outstanding -> vmcnt(4) proves them done. kt=14: nothing newer
        // in flight, tile-15 loads are the newest -> full drain.
        if (kt < 14) {
            asm volatile("s_waitcnt vmcnt(4)" ::: "memory");
            __builtin_amdgcn_s_barrier();
        } else if (kt == 14) {
            asm volatile("s_waitcnt vmcnt(0)" ::: "memory");
            __builtin_amdgcn_s_barrier();
        }
        cur = (cur == 2) ? 0 : cur + 1;
    }

    // epilogue: lane q = q0+wq+l31; dh = dt*32 + 8g + 4hi + m
    float inv = __builtin_amdgcn_rcpf(osum[0]);
    size_t rowbase = (size_t)(b * SEQ + q0 + wq + l31) * DIM + h * 64 + hi4;
#pragma unroll
    for (int dt = 0; dt < 2; ++dt) {
#pragma unroll
        for (int g = 0; g < 4; ++g) {
            u16x4 pk = { f2bf(o[dt][4 * g + 0] * inv), f2bf(o[dt][4 * g + 1] * inv),
                         f2bf(o[dt][4 * g + 2] * inv), f2bf(o[dt][4 * g + 3] * inv) };
            *(u16x4*)&out[rowbase + dt * 32 + 8 * g] = pk;
        }
    }
}

extern "C" void kernel_launch(void* const* d_in, const int* in_sizes, int n_in,
                              void* d_out, int out_size, void* d_ws, size_t ws_size,
                              hipStream_t stream) {
    const float* x          = (const float*)d_in[0];  // (8,1024,768) fp32
    const float* w_qkv      = (const float*)d_in[1];  // (768,2304) fp32
    const float* bias_table = (const float*)d_in[2];  // (12,2047) fp32
    const float* w_out      = (const float*)d_in[3];  // (768,768) fp32
    const float* b_out      = (const float*)d_in[4];  // (768,) fp32
    float* out = (float*)d_out;                       // (8,1024,768) fp32

    char* ws = (char*)d_ws;
    u16* ws_qkv        = (u16*)(ws);                   // 37,748,736 B
    u16* ws_attn       = (u16*)(ws + 37748736);        // 12,582,912 B
    u16* ws_xb         = (u16*)(ws + 50331648);        // 12,582,912 B
    u16* ws_wqkvT      = (u16*)(ws + 62914560);        //  3,538,944 B
    u16* ws_woutT      = (u16*)(ws + 66453504);        //  1,179,648 B
    _Float16* ws_vT    = (_Float16*)(ws + 67633152);   // 12,582,912 B (tot 80.2MB)

    cvt_k<<<8 * 1024 * 768 / 1024, 256, 0, stream>>>(x, ws_xb);
    transpose_k<<<dim3(2304 / 32, 768 / 32), 256, 0, stream>>>(w_qkv, ws_wqkvT, 768, 2304);
    transpose_k<<<dim3(768 / 32, 768 / 32), 256, 0, stream>>>(w_out, ws_woutT, 768, 768);

    // qkv = x @ w_qkv : M=8192, N=2304, K=768  (gridDim.x = 64, %8==0)
    gemm_bt<0, u16><<<dim3(8192 / 128, 2304 / 128), 256, 0, stream>>>(
        ws_xb, ws_wqkvT, nullptr, ws_qkv, 8192, 2304, 768);

    vt_k<<<dim3(SEQ / 32, 2, 8 * NH), 256, 0, stream>>>(ws_qkv, ws_vT);

    attn_k<<<dim3(8 * NH, SEQ / 128, 1), 256, 0, stream>>>(ws_qkv, ws_vT, bias_table, ws_attn);

    // out = attn @ w_out + b_out : M=8192, N=768, K=768  (gridDim.x = 64, %8==0)
    gemm_bt<1, float><<<dim3(8192 / 128, 768 / 128), 256, 0, stream>>>(
        ws_attn, ws_woutT, b_out, out, 8192, 768, 768);
}